// Round 4
// baseline (138.633 us; speedup 1.0000x reference)
//
#include <hip/hip_runtime.h>

typedef float f32x4 __attribute__((ext_vector_type(4)));
typedef float f32x16 __attribute__((ext_vector_type(16)));
typedef short s16x8 __attribute__((ext_vector_type(8)));
typedef short s16x4 __attribute__((ext_vector_type(4)));
typedef unsigned short u16;

#define NB 8
#define NC 64
#define NN 4096

// float -> bf16 bits, round-to-nearest-even
__device__ __forceinline__ u16 f2bf_rne(float f) {
    unsigned u = __float_as_uint(f);
    u += 0x7FFFu + ((u >> 16) & 1u);
    return (u16)(u >> 16);
}
__device__ __forceinline__ float bf2f(u16 v) {
    return __uint_as_float(((unsigned)v) << 16);
}
// pack two f32 -> one u32 of 2 bf16 (RNE), lo = first arg
__device__ __forceinline__ unsigned cvt_pk_bf16(float lo, float hi) {
    unsigned r;
    asm("v_cvt_pk_bf16_f32 %0, %1, %2" : "=v"(r) : "v"(lo), "v"(hi));
    return r;
}
// swap: a' = {a.lanes0-31, b.lanes0-31}, b' = {a.lanes32-63, b.lanes32-63}
__device__ __forceinline__ void pl32_swap(unsigned &a, unsigned &b) {
    asm("v_permlane32_swap_b32 %0, %1" : "+v"(a), "+v"(b));
}
// 2^x via the hardware transcendental unit (v_exp_f32)
__device__ __forceinline__ float exp2_hw(float x) {
    return __builtin_amdgcn_exp2f(x);
}

#define Z16 ((f32x16){0.f,0.f,0.f,0.f,0.f,0.f,0.f,0.f,0.f,0.f,0.f,0.f,0.f,0.f,0.f,0.f})

// ---------------------------------------------------------------------------
// Kernel 1: W' = [Wh(64); Wf(8); Wg(8)] (80x64) @ x[b] via MFMA.
// Cooperative LDS staging with f32x4 vector loads. Wf rows pre-scaled by
// log2(e) (attention uses exp2 directly).
// v4: Qw/Gw stored as [B][N][16] bf16 with elements 8..15 ZEROED, so the
// attention kernel's K=16 fragment loads are unconditional (hi half reads
// zeros) with no per-chunk zero-init and full coalescing.
// ---------------------------------------------------------------------------
__global__ __launch_bounds__(256, 4)
void precompute_qgh(const float* __restrict__ x,
                    const float* __restrict__ Wf,
                    const float* __restrict__ Wg,
                    const float* __restrict__ Wh,
                    u16* __restrict__ Qw, u16* __restrict__ Gw,
                    u16* __restrict__ Hw)
{
    const int b  = blockIdx.y;
    const int n0 = blockIdx.x * 64;
    const int t  = threadIdx.x;
    const int wave = t >> 6, lane = t & 63, col = lane & 15, quad = lane >> 4;
    const float* xb = x + (size_t)b * NC * NN;

    __shared__ __align__(16) u16 WL[80][72];   // rows 0..63 Wh, 64..71 Wf, 72..79 Wg
    __shared__ __align__(16) u16 XT[64][72];   // x tile transposed: [n_local][c]

    // stage W' (5120 f32 = 5 x f32x4 per thread); Wf scaled by log2(e)
    #pragma unroll
    for (int r5 = 0; r5 < 5; r5++) {
        int v = r5 * 256 + t;
        int m = v >> 4, ks = (v & 15) << 2;
        const float* src = (m < 64) ? (Wh + m * 64 + ks)
                         : (m < 72) ? (Wf + (m - 64) * 64 + ks)
                                    : (Wg + (m - 72) * 64 + ks);
        const float scl = (m >= 64 && m < 72) ? 1.44269504088896f : 1.0f;
        f32x4 wv = *(const f32x4*)src;
        *(unsigned*)&WL[m][ks]     = (unsigned)f2bf_rne(wv[0] * scl) | ((unsigned)f2bf_rne(wv[1] * scl) << 16);
        *(unsigned*)&WL[m][ks + 2] = (unsigned)f2bf_rne(wv[2] * scl) | ((unsigned)f2bf_rne(wv[3] * scl) << 16);
    }
    // stage x tile (64c x 64n f32 = 4 x f32x4 per thread), transposed into XT
    #pragma unroll
    for (int r4 = 0; r4 < 4; r4++) {
        int v = r4 * 256 + t;
        int c = v >> 4, ns = (v & 15) << 2;
        f32x4 xv = *(const f32x4*)(xb + (size_t)c * NN + n0 + ns);
        #pragma unroll
        for (int e = 0; e < 4; e++) XT[ns + e][c] = f2bf_rne(xv[e]);
    }
    __syncthreads();

    const int n = n0 + wave * 16 + col;
    s16x8 bfrag[2], afrag[5][2];
    #pragma unroll
    for (int s = 0; s < 2; s++)
        bfrag[s] = *(const s16x8*)&XT[wave * 16 + col][s * 32 + quad * 8];
    #pragma unroll
    for (int mt = 0; mt < 5; mt++)
        #pragma unroll
        for (int s = 0; s < 2; s++)
            afrag[mt][s] = *(const s16x8*)&WL[mt * 16 + col][s * 32 + quad * 8];

    f32x4 d[5];
    #pragma unroll
    for (int mt = 0; mt < 5; mt++) d[mt] = (f32x4){0.f, 0.f, 0.f, 0.f};
    #pragma unroll
    for (int s = 0; s < 2; s++)
        #pragma unroll
        for (int mt = 0; mt < 5; mt++)
            d[mt] = __builtin_amdgcn_mfma_f32_16x16x32_bf16(afrag[mt][s], bfrag[s], d[mt], 0, 0, 0);

    // D[row=quad*4+r][col]: Wh rows -> Hw [c][n]
    u16* Hb = Hw + (size_t)b * NC * NN;
    #pragma unroll
    for (int mt = 0; mt < 4; mt++)
        #pragma unroll
        for (int r = 0; r < 4; r++)
            Hb[(size_t)(mt * 16 + quad * 4 + r) * NN + n] = f2bf_rne(d[mt][r]);

    // Q/G rows -> [n][16] padded layout. quad0 -> Q[0..3] (+zeros 8..15),
    // quad1 -> Q[4..7], quad2 -> G[0..3] (+zeros), quad3 -> G[4..7].
    union { s16x4 v; u16 e[4]; } pk4;
    #pragma unroll
    for (int r = 0; r < 4; r++) pk4.e[r] = f2bf_rne(d[4][r]);
    u16* base = (quad < 2 ? Qw : Gw) + ((size_t)b * NN + n) * 16;
    *(s16x4*)(base + (quad & 1) * 4) = pk4.v;
    if ((quad & 1) == 0) {
        s16x8 z;
        #pragma unroll
        for (int q = 0; q < 8; q++) ((u16*)&z)[q] = 0;
        *(s16x8*)(base + 8) = z;
    }
}

// ---------------------------------------------------------------------------
// Kernel 2 v4: fused flash attention, BARRIER-FREE / LDS-FREE main loop.
// Grid (128, 8): block owns 32 i-rows; each of the 4 waves independently
// processes j-quarter wave*1024 in 32-j chunks (no shared state in loop).
// Per chunk: S^T = mfma32(G[j0..j0+32], Q) (K=8 zero-padded via [n][16]
// layout); exp2; P built in-register (cvt_pk + permlane32_swap); row-sum via
// ones-A MFMA on the same bf16 P; PV reads V A-frags DIRECTLY from global
// (L2-resident Hw, 64B/row per chunk).
// Epilogue: 4 partials tree-combined through small f32 LDS (stride-36 rows,
// conflict-free), then normalize * gamma + residual, f32 store.
// ---------------------------------------------------------------------------
__global__ __launch_bounds__(256, 4)
void attention_fused(const u16* __restrict__ Qw, const u16* __restrict__ Gw,
                     const u16* __restrict__ Hw,
                     const float* __restrict__ x, const float* __restrict__ gamma,
                     float* __restrict__ out)
{
    const int b  = blockIdx.y;
    const int i0 = blockIdx.x * 32;
    const int t  = threadIdx.x;
    const int wave = t >> 6, lane = t & 63, col = lane & 31, hi = lane >> 5;

    __shared__ __align__(16) float R0[64][36];   // 9216 B
    __shared__ __align__(16) float R1[64][36];   // 9216 B
    __shared__ float L0[32], L1[32];

    const u16* Qb = Qw + (size_t)b * NN * 16;
    const u16* Gb = Gw + (size_t)b * NN * 16;
    const u16* Hb = Hw + (size_t)b * NC * NN;

    const float g = gamma[0];

    // Q fragment (B-operand of S^T): B[k=hi*8+kk][n=i=col]; k>=8 zeros from layout
    s16x8 qf = *(const s16x8*)(Qb + (size_t)(i0 + col) * 16 + hi * 8);

    s16x8 ones;
    #pragma unroll
    for (int q = 0; q < 8; q++) ((u16*)&ones)[q] = 0x3F80;   // bf16 1.0

    f32x16 oacc[2];
    oacc[0] = Z16; oacc[1] = Z16;
    f32x16 lacc = Z16;

    const int jbase = wave * 1024;

    // prefetch G fragment for chunk 0 (A[m=j][k]; k>=8 zeros from layout)
    s16x8 ga = *(const s16x8*)(Gb + (size_t)(jbase + col) * 16 + hi * 8);

    for (int cc = 0; cc < 32; cc++) {
        const int j0 = jbase + cc * 32;
        // V A-frags direct from global: A[m=c][k = s2*16 + hi*8 + kk]
        const u16* hrow = Hb + (size_t)col * NN + j0 + hi * 8;
        s16x8 va00 = *(const s16x8*)(hrow);
        s16x8 va01 = *(const s16x8*)(hrow + 16);
        s16x8 va10 = *(const s16x8*)(hrow + (size_t)32 * NN);
        s16x8 va11 = *(const s16x8*)(hrow + (size_t)32 * NN + 16);

        f32x16 S = __builtin_amdgcn_mfma_f32_32x32x16_bf16(ga, qf, Z16, 0, 0, 0);
        // prefetch next chunk's G (last iter overreads into next region - benign)
        ga = *(const s16x8*)(Gb + (size_t)(j0 + 32 + col) * 16 + hi * 8);

        #pragma unroll
        for (int r = 0; r < 16; r++) S[r] = exp2_hw(S[r]);

        #pragma unroll
        for (int s2 = 0; s2 < 2; s2++) {
            unsigned w0 = cvt_pk_bf16(S[8*s2+0], S[8*s2+1]);
            unsigned w2 = cvt_pk_bf16(S[8*s2+4], S[8*s2+5]);
            unsigned w1 = cvt_pk_bf16(S[8*s2+2], S[8*s2+3]);
            unsigned w3 = cvt_pk_bf16(S[8*s2+6], S[8*s2+7]);
            pl32_swap(w0, w2);   // -> bfrag words 0 and 2
            pl32_swap(w1, w3);   // -> bfrag words 1 and 3
            union { s16x8 v; unsigned u[4]; } pb;
            pb.u[0] = w0; pb.u[1] = w1; pb.u[2] = w2; pb.u[3] = w3;
            // row-sum: ones-A MFMA on same bf16 P (all regs = partial l[i=col])
            lacc = __builtin_amdgcn_mfma_f32_32x32x16_bf16(ones, pb.v, lacc, 0, 0, 0);
            oacc[0] = __builtin_amdgcn_mfma_f32_32x32x16_bf16(s2 ? va01 : va00, pb.v, oacc[0], 0, 0, 0);
            oacc[1] = __builtin_amdgcn_mfma_f32_32x32x16_bf16(s2 ? va11 : va10, pb.v, oacc[1], 0, 0, 0);
        }
    }

    // ---- epilogue: tree-combine 4 wave partials, normalize, residual ----
    // oacc[ct][r] = O_part[c = ct*32 + (r&3)+8*(r>>2)+4*hi][i = i0+col]
    // Phase A: waves 1,3 publish partials.
    if (wave & 1) {
        float (*R)[36] = (wave == 1) ? R0 : R1;
        float* L = (wave == 1) ? L0 : L1;
        #pragma unroll
        for (int ct = 0; ct < 2; ct++)
            #pragma unroll
            for (int r = 0; r < 16; r++) {
                int c = ct * 32 + (r & 3) + 8 * (r >> 2) + 4 * hi;
                R[c][col] = oacc[ct][r];
            }
        if (hi == 0) L[col] = lacc[0];
    }
    __syncthreads();
    // Phase B: waves 0,2 absorb their partner's partial.
    float lsum = lacc[0];
    if (!(wave & 1)) {
        float (*R)[36] = (wave == 0) ? R0 : R1;
        float* L = (wave == 0) ? L0 : L1;
        #pragma unroll
        for (int ct = 0; ct < 2; ct++)
            #pragma unroll
            for (int r = 0; r < 16; r++) {
                int c = ct * 32 + (r & 3) + 8 * (r >> 2) + 4 * hi;
                oacc[ct][r] += R[c][col];
            }
        lsum += L[col];
    }
    // Phase C: wave 2 republishes (w2+w3) sum. (In-wave RAW order with its
    // own Phase-B reads of R1; no other wave touches R1 in between.)
    if (wave == 2) {
        #pragma unroll
        for (int ct = 0; ct < 2; ct++)
            #pragma unroll
            for (int r = 0; r < 16; r++) {
                int c = ct * 32 + (r & 3) + 8 * (r >> 2) + 4 * hi;
                R1[c][col] = oacc[ct][r];
            }
        if (hi == 0) L1[col] = lsum;
    }
    __syncthreads();
    // Phase D: wave 0 finalizes: total O, scale = gamma / l_total.
    if (wave == 0) {
        lsum += L1[col];
        const float scale = g / lsum;
        #pragma unroll
        for (int ct = 0; ct < 2; ct++)
            #pragma unroll
            for (int r = 0; r < 16; r++) {
                int c = ct * 32 + (r & 3) + 8 * (r >> 2) + 4 * hi;
                R0[c][col] = (oacc[ct][r] + R1[c][col]) * scale;
            }
    }
    __syncthreads();

    // Phase 3: all 256 threads: coalesced residual add + f32 store.
    const int oc = t >> 2, q4 = t & 3;
    const float* xr = x   + ((size_t)b * NC + oc) * NN + i0 + q4 * 8;
    float*    orow  = out + ((size_t)b * NC + oc) * NN + i0 + q4 * 8;
    f32x4 r0v = *(const f32x4*)&R0[oc][q4 * 8];
    f32x4 r1v = *(const f32x4*)&R0[oc][q4 * 8 + 4];
    f32x4 x0 = *(const f32x4*)(xr);
    f32x4 x1 = *(const f32x4*)(xr + 4);
    *(f32x4*)(orow)     = r0v + x0;
    *(f32x4*)(orow + 4) = r1v + x1;
}

extern "C" void kernel_launch(void* const* d_in, const int* in_sizes, int n_in,
                              void* d_out, int out_size, void* d_ws, size_t ws_size,
                              hipStream_t stream) {
    const float* x     = (const float*)d_in[0];
    const float* Wf    = (const float*)d_in[1];
    const float* Wg    = (const float*)d_in[2];
    const float* Wh    = (const float*)d_in[3];
    const float* gamma = (const float*)d_in[4];
    float* out = (float*)d_out;

    u16* Qw = (u16*)d_ws;                       // [B][N][16] (top 8 zeroed)
    u16* Gw = Qw + (size_t)NB * NN * 16;        // [B][N][16] (top 8 zeroed)
    u16* Hw = Gw + (size_t)NB * NN * 16;        // [B][C][N]

    precompute_qgh<<<dim3(64, NB), 256, 0, stream>>>(x, Wf, Wg, Wh, Qw, Gw, Hw);
    attention_fused<<<dim3(128, NB), 256, 0, stream>>>(Qw, Gw, Hw, x, gamma, out);
}

// Round 5
// 134.772 us; speedup vs baseline: 1.0286x; 1.0286x over previous
//
#include <hip/hip_runtime.h>

typedef float f32x4 __attribute__((ext_vector_type(4)));
typedef float f32x16 __attribute__((ext_vector_type(16)));
typedef short s16x8 __attribute__((ext_vector_type(8)));
typedef short s16x4 __attribute__((ext_vector_type(4)));
typedef unsigned short u16;

#define NB 8
#define NC 64
#define NN 4096

// float -> bf16 bits, round-to-nearest-even
__device__ __forceinline__ u16 f2bf_rne(float f) {
    unsigned u = __float_as_uint(f);
    u += 0x7FFFu + ((u >> 16) & 1u);
    return (u16)(u >> 16);
}
__device__ __forceinline__ float bf2f(u16 v) {
    return __uint_as_float(((unsigned)v) << 16);
}
// pack two f32 -> one u32 of 2 bf16 (RNE), lo = first arg
__device__ __forceinline__ unsigned cvt_pk_bf16(float lo, float hi) {
    unsigned r;
    asm("v_cvt_pk_bf16_f32 %0, %1, %2" : "=v"(r) : "v"(lo), "v"(hi));
    return r;
}
// swap: a' = {a.lanes0-31, b.lanes0-31}, b' = {a.lanes32-63, b.lanes32-63}
__device__ __forceinline__ void pl32_swap(unsigned &a, unsigned &b) {
    asm("v_permlane32_swap_b32 %0, %1" : "+v"(a), "+v"(b));
}
// 2^x via the hardware transcendental unit (v_exp_f32)
__device__ __forceinline__ float exp2_hw(float x) {
    return __builtin_amdgcn_exp2f(x);
}

#define Z16 ((f32x16){0.f,0.f,0.f,0.f,0.f,0.f,0.f,0.f,0.f,0.f,0.f,0.f,0.f,0.f,0.f,0.f})

// ---------------------------------------------------------------------------
// Kernel 1: W' = [Wh(64); Wf(8); Wg(8)] (80x64) @ x[b] via MFMA.
// Cooperative LDS staging with f32x4 vector loads. Wf rows pre-scaled by
// log2(e) (attention uses exp2 directly). Qw/Gw stored as [B][N][16] bf16
// with elements 8..15 ZEROED -> unconditional K=16 fragment loads.
// ---------------------------------------------------------------------------
__global__ __launch_bounds__(256, 4)
void precompute_qgh(const float* __restrict__ x,
                    const float* __restrict__ Wf,
                    const float* __restrict__ Wg,
                    const float* __restrict__ Wh,
                    u16* __restrict__ Qw, u16* __restrict__ Gw,
                    u16* __restrict__ Hw)
{
    const int b  = blockIdx.y;
    const int n0 = blockIdx.x * 64;
    const int t  = threadIdx.x;
    const int wave = t >> 6, lane = t & 63, col = lane & 15, quad = lane >> 4;
    const float* xb = x + (size_t)b * NC * NN;

    __shared__ __align__(16) u16 WL[80][72];   // rows 0..63 Wh, 64..71 Wf, 72..79 Wg
    __shared__ __align__(16) u16 XT[64][72];   // x tile transposed: [n_local][c]

    // stage W' (5120 f32 = 5 x f32x4 per thread); Wf scaled by log2(e)
    #pragma unroll
    for (int r5 = 0; r5 < 5; r5++) {
        int v = r5 * 256 + t;
        int m = v >> 4, ks = (v & 15) << 2;
        const float* src = (m < 64) ? (Wh + m * 64 + ks)
                         : (m < 72) ? (Wf + (m - 64) * 64 + ks)
                                    : (Wg + (m - 72) * 64 + ks);
        const float scl = (m >= 64 && m < 72) ? 1.44269504088896f : 1.0f;
        f32x4 wv = *(const f32x4*)src;
        *(unsigned*)&WL[m][ks]     = (unsigned)f2bf_rne(wv[0] * scl) | ((unsigned)f2bf_rne(wv[1] * scl) << 16);
        *(unsigned*)&WL[m][ks + 2] = (unsigned)f2bf_rne(wv[2] * scl) | ((unsigned)f2bf_rne(wv[3] * scl) << 16);
    }
    // stage x tile (64c x 64n f32 = 4 x f32x4 per thread), transposed into XT
    #pragma unroll
    for (int r4 = 0; r4 < 4; r4++) {
        int v = r4 * 256 + t;
        int c = v >> 4, ns = (v & 15) << 2;
        f32x4 xv = *(const f32x4*)(xb + (size_t)c * NN + n0 + ns);
        #pragma unroll
        for (int e = 0; e < 4; e++) XT[ns + e][c] = f2bf_rne(xv[e]);
    }
    __syncthreads();

    const int n = n0 + wave * 16 + col;
    s16x8 bfrag[2], afrag[5][2];
    #pragma unroll
    for (int s = 0; s < 2; s++)
        bfrag[s] = *(const s16x8*)&XT[wave * 16 + col][s * 32 + quad * 8];
    #pragma unroll
    for (int mt = 0; mt < 5; mt++)
        #pragma unroll
        for (int s = 0; s < 2; s++)
            afrag[mt][s] = *(const s16x8*)&WL[mt * 16 + col][s * 32 + quad * 8];

    f32x4 d[5];
    #pragma unroll
    for (int mt = 0; mt < 5; mt++) d[mt] = (f32x4){0.f, 0.f, 0.f, 0.f};
    #pragma unroll
    for (int s = 0; s < 2; s++)
        #pragma unroll
        for (int mt = 0; mt < 5; mt++)
            d[mt] = __builtin_amdgcn_mfma_f32_16x16x32_bf16(afrag[mt][s], bfrag[s], d[mt], 0, 0, 0);

    // D[row=quad*4+r][col]: Wh rows -> Hw [c][n]
    u16* Hb = Hw + (size_t)b * NC * NN;
    #pragma unroll
    for (int mt = 0; mt < 4; mt++)
        #pragma unroll
        for (int r = 0; r < 4; r++)
            Hb[(size_t)(mt * 16 + quad * 4 + r) * NN + n] = f2bf_rne(d[mt][r]);

    // Q/G rows -> [n][16] padded layout. quad0 -> Q[0..3] (+zeros 8..15),
    // quad1 -> Q[4..7], quad2 -> G[0..3] (+zeros), quad3 -> G[4..7].
    union { s16x4 v; u16 e[4]; } pk4;
    #pragma unroll
    for (int r = 0; r < 4; r++) pk4.e[r] = f2bf_rne(d[4][r]);
    u16* base = (quad < 2 ? Qw : Gw) + ((size_t)b * NN + n) * 16;
    *(s16x4*)(base + (quad & 1) * 4) = pk4.v;
    if ((quad & 1) == 0) {
        s16x8 z;
        #pragma unroll
        for (int q = 0; q < 8; q++) ((u16*)&z)[q] = 0;
        *(s16x8*)(base + 8) = z;
    }
}

// ---------------------------------------------------------------------------
// Kernel 2 v5: fused flash attention, barrier-free/LDS-free main loop WITH
// register double-buffered V + G (one-chunk prefetch distance hides L2
// latency — round 4's regression was consuming V loads immediately).
// Grid (128, 8): block owns 32 i-rows; each of the 4 waves independently
// processes j-quarter wave*1024 in 32-j chunks.
// Per chunk: S^T = mfma32(G, Q) (K=8 zero-padded layout); exp2; row-sum via
// 16 VALU adds on f32 P (hi-halves combined by permlane32_swap in epilogue —
// replaces the ones-MFMA, freeing 16 VGPR + 2 MFMA/chunk); P built
// in-register (cvt_pk + permlane32_swap); PV from prefetched V regs.
// Epilogue: 4 partials tree-combined through f32 LDS, normalize*gamma +
// residual, f32 store.
// ---------------------------------------------------------------------------
__global__ __launch_bounds__(256, 4)
void attention_fused(const u16* __restrict__ Qw, const u16* __restrict__ Gw,
                     const u16* __restrict__ Hw,
                     const float* __restrict__ x, const float* __restrict__ gamma,
                     float* __restrict__ out)
{
    const int b  = blockIdx.y;
    const int i0 = blockIdx.x * 32;
    const int t  = threadIdx.x;
    const int wave = t >> 6, lane = t & 63, col = lane & 31, hi = lane >> 5;

    __shared__ __align__(16) float R0[64][36];   // 9216 B
    __shared__ __align__(16) float R1[64][36];   // 9216 B
    __shared__ float L0[32], L1[32];

    const u16* Qb = Qw + (size_t)b * NN * 16;
    const u16* Gb = Gw + (size_t)b * NN * 16;
    const u16* Hb = Hw + (size_t)b * NC * NN;

    const float g = gamma[0];

    // Q fragment (B-operand of S^T): B[k=hi*8+kk][n=i=col]; k>=8 zeros from layout
    s16x8 qf = *(const s16x8*)(Qb + (size_t)(i0 + col) * 16 + hi * 8);

    f32x16 oacc[2];
    oacc[0] = Z16; oacc[1] = Z16;
    float lsum = 0.f;

    const int jbase = wave * 1024;
    const u16* hrow = Hb + (size_t)col * NN + jbase + hi * 8;

    // prefetch chunk 0 (G A-frag + 4 V A-frags)
    s16x8 ga  = *(const s16x8*)(Gb + (size_t)(jbase + col) * 16 + hi * 8);
    s16x8 va0 = *(const s16x8*)(hrow);
    s16x8 va1 = *(const s16x8*)(hrow + 16);
    s16x8 va2 = *(const s16x8*)(hrow + (size_t)32 * NN);
    s16x8 va3 = *(const s16x8*)(hrow + (size_t)32 * NN + 16);

    for (int cc = 0; cc < 32; cc++) {
        const int j0 = jbase + cc * 32;
        // issue prefetch for chunk cc+1 FIRST (consumed next iteration;
        // last-iter overread lands in adjacent ws regions — benign)
        const u16* hn = Hb + (size_t)col * NN + j0 + 32 + hi * 8;
        s16x8 gan = *(const s16x8*)(Gb + (size_t)(j0 + 32 + col) * 16 + hi * 8);
        s16x8 vn0 = *(const s16x8*)(hn);
        s16x8 vn1 = *(const s16x8*)(hn + 16);
        s16x8 vn2 = *(const s16x8*)(hn + (size_t)32 * NN);
        s16x8 vn3 = *(const s16x8*)(hn + (size_t)32 * NN + 16);

        f32x16 S = __builtin_amdgcn_mfma_f32_32x32x16_bf16(ga, qf, Z16, 0, 0, 0);
        #pragma unroll
        for (int r = 0; r < 16; r++) S[r] = exp2_hw(S[r]);
        // partial row-sum on f32 P (this lane's 16 j'-slots for i=col)
        #pragma unroll
        for (int r = 0; r < 16; r++) lsum += S[r];

        #pragma unroll
        for (int s2 = 0; s2 < 2; s2++) {
            unsigned w0 = cvt_pk_bf16(S[8*s2+0], S[8*s2+1]);
            unsigned w2 = cvt_pk_bf16(S[8*s2+4], S[8*s2+5]);
            unsigned w1 = cvt_pk_bf16(S[8*s2+2], S[8*s2+3]);
            unsigned w3 = cvt_pk_bf16(S[8*s2+6], S[8*s2+7]);
            pl32_swap(w0, w2);   // -> bfrag words 0 and 2
            pl32_swap(w1, w3);   // -> bfrag words 1 and 3
            union { s16x8 v; unsigned u[4]; } pb;
            pb.u[0] = w0; pb.u[1] = w1; pb.u[2] = w2; pb.u[3] = w3;
            oacc[0] = __builtin_amdgcn_mfma_f32_32x32x16_bf16(s2 ? va1 : va0, pb.v, oacc[0], 0, 0, 0);
            oacc[1] = __builtin_amdgcn_mfma_f32_32x32x16_bf16(s2 ? va3 : va2, pb.v, oacc[1], 0, 0, 0);
        }
        ga = gan; va0 = vn0; va1 = vn1; va2 = vn2; va3 = vn3;
    }

    // combine hi-halves of lsum: lane i and lane i+32 hold the two j-halves
    {
        unsigned a = __float_as_uint(lsum), c = a;
        pl32_swap(a, c);   // a = [lo;lo], c = [hi;hi]
        lsum = __uint_as_float(a) + __uint_as_float(c);
    }

    // ---- epilogue: tree-combine 4 wave partials, normalize, residual ----
    // oacc[ct][r] = O_part[c = ct*32 + (r&3)+8*(r>>2)+4*hi][i = i0+col]
    if (wave & 1) {
        float (*R)[36] = (wave == 1) ? R0 : R1;
        float* L = (wave == 1) ? L0 : L1;
        #pragma unroll
        for (int ct = 0; ct < 2; ct++)
            #pragma unroll
            for (int r = 0; r < 16; r++) {
                int c = ct * 32 + (r & 3) + 8 * (r >> 2) + 4 * hi;
                R[c][col] = oacc[ct][r];
            }
        if (hi == 0) L[col] = lsum;
    }
    __syncthreads();
    if (!(wave & 1)) {
        float (*R)[36] = (wave == 0) ? R0 : R1;
        float* L = (wave == 0) ? L0 : L1;
        #pragma unroll
        for (int ct = 0; ct < 2; ct++)
            #pragma unroll
            for (int r = 0; r < 16; r++) {
                int c = ct * 32 + (r & 3) + 8 * (r >> 2) + 4 * hi;
                oacc[ct][r] += R[c][col];
            }
        lsum += L[col];
    }
    // wave 2 republishes (w2+w3) sum
    if (wave == 2) {
        #pragma unroll
        for (int ct = 0; ct < 2; ct++)
            #pragma unroll
            for (int r = 0; r < 16; r++) {
                int c = ct * 32 + (r & 3) + 8 * (r >> 2) + 4 * hi;
                R1[c][col] = oacc[ct][r];
            }
        if (hi == 0) L1[col] = lsum;
    }
    __syncthreads();
    // wave 0 finalizes: total O, scale = gamma / l_total
    if (wave == 0) {
        lsum += L1[col];
        const float scale = g / lsum;
        #pragma unroll
        for (int ct = 0; ct < 2; ct++)
            #pragma unroll
            for (int r = 0; r < 16; r++) {
                int c = ct * 32 + (r & 3) + 8 * (r >> 2) + 4 * hi;
                R0[c][col] = (oacc[ct][r] + R1[c][col]) * scale;
            }
    }
    __syncthreads();

    // all 256 threads: coalesced residual add + f32 store
    const int oc = t >> 2, q4 = t & 3;
    const float* xr = x   + ((size_t)b * NC + oc) * NN + i0 + q4 * 8;
    float*    orow  = out + ((size_t)b * NC + oc) * NN + i0 + q4 * 8;
    f32x4 r0v = *(const f32x4*)&R0[oc][q4 * 8];
    f32x4 r1v = *(const f32x4*)&R0[oc][q4 * 8 + 4];
    f32x4 x0 = *(const f32x4*)(xr);
    f32x4 x1 = *(const f32x4*)(xr + 4);
    *(f32x4*)(orow)     = r0v + x0;
    *(f32x4*)(orow + 4) = r1v + x1;
}

extern "C" void kernel_launch(void* const* d_in, const int* in_sizes, int n_in,
                              void* d_out, int out_size, void* d_ws, size_t ws_size,
                              hipStream_t stream) {
    const float* x     = (const float*)d_in[0];
    const float* Wf    = (const float*)d_in[1];
    const float* Wg    = (const float*)d_in[2];
    const float* Wh    = (const float*)d_in[3];
    const float* gamma = (const float*)d_in[4];
    float* out = (float*)d_out;

    u16* Qw = (u16*)d_ws;                       // [B][N][16] (top 8 zeroed)
    u16* Gw = Qw + (size_t)NB * NN * 16;        // [B][N][16] (top 8 zeroed)
    u16* Hw = Gw + (size_t)NB * NN * 16;        // [B][C][N]

    precompute_qgh<<<dim3(64, NB), 256, 0, stream>>>(x, Wf, Wg, Wh, Qw, Gw, Hw);
    attention_fused<<<dim3(128, NB), 256, 0, stream>>>(Qw, Gw, Hw, x, gamma, out);
}

// Round 6
// 106.100 us; speedup vs baseline: 1.3066x; 1.2702x over previous
//
#include <hip/hip_runtime.h>

typedef float f32x4 __attribute__((ext_vector_type(4)));
typedef float f32x16 __attribute__((ext_vector_type(16)));
typedef short s16x8 __attribute__((ext_vector_type(8)));
typedef short s16x4 __attribute__((ext_vector_type(4)));
typedef unsigned short u16;

#define NB 8
#define NC 64
#define NN 4096

// float -> bf16 bits, round-to-nearest-even
__device__ __forceinline__ u16 f2bf_rne(float f) {
    unsigned u = __float_as_uint(f);
    u += 0x7FFFu + ((u >> 16) & 1u);
    return (u16)(u >> 16);
}
__device__ __forceinline__ float bf2f(u16 v) {
    return __uint_as_float(((unsigned)v) << 16);
}
// pack two f32 -> one u32 of 2 bf16 (RNE), lo = first arg
__device__ __forceinline__ unsigned cvt_pk_bf16(float lo, float hi) {
    unsigned r;
    asm("v_cvt_pk_bf16_f32 %0, %1, %2" : "=v"(r) : "v"(lo), "v"(hi));
    return r;
}
// swap: a' = {a.lanes0-31, b.lanes0-31}, b' = {a.lanes32-63, b.lanes32-63}
__device__ __forceinline__ void pl32_swap(unsigned &a, unsigned &b) {
    asm("v_permlane32_swap_b32 %0, %1" : "+v"(a), "+v"(b));
}
// 2^x via the hardware transcendental unit (v_exp_f32)
__device__ __forceinline__ float exp2_hw(float x) {
    return __builtin_amdgcn_exp2f(x);
}

#define Z16 ((f32x16){0.f,0.f,0.f,0.f,0.f,0.f,0.f,0.f,0.f,0.f,0.f,0.f,0.f,0.f,0.f,0.f})

// ---------------------------------------------------------------------------
// Kernel 1: W' = [Wh(64); Wf(8); Wg(8)] (80x64) @ x[b] via MFMA.
// Wf rows pre-scaled by log2(e). Qw/Gw stored [B][N][16] bf16, top 8 zeroed.
// v6: H is written in PV-B-FRAGMENT order (Hf): for j-slice s (16 j),
// chalf (32 c), lane l, kk:  Hf[..] = H[chalf*32+(l&31)][s*16+(l>>5)*8+kk].
// This makes the attention kernel's V loads single fully-coalesced dwordx4
// per fragment (round 5 was TA-bound: 32 lines touched per V load, 25%
// sector use). Produced via LDS transpose: d -> Hl[c][n] -> ds_read_b128
// in fragment order -> coalesced global store.
// ---------------------------------------------------------------------------
__global__ __launch_bounds__(256, 4)
void precompute_qgh(const float* __restrict__ x,
                    const float* __restrict__ Wf,
                    const float* __restrict__ Wg,
                    const float* __restrict__ Wh,
                    u16* __restrict__ Qw, u16* __restrict__ Gw,
                    u16* __restrict__ Hf)
{
    const int b  = blockIdx.y;
    const int n0 = blockIdx.x * 64;
    const int t  = threadIdx.x;
    const int wave = t >> 6, lane = t & 63, col = lane & 15, quad = lane >> 4;
    const float* xb = x + (size_t)b * NC * NN;

    __shared__ __align__(16) u16 WL[80][72];   // rows 0..63 Wh, 64..71 Wf, 72..79 Wg
    __shared__ __align__(16) u16 XT[64][72];   // x tile transposed: [n_local][c]

    // stage W' (5120 f32 = 5 x f32x4 per thread); Wf scaled by log2(e)
    #pragma unroll
    for (int r5 = 0; r5 < 5; r5++) {
        int v = r5 * 256 + t;
        int m = v >> 4, ks = (v & 15) << 2;
        const float* src = (m < 64) ? (Wh + m * 64 + ks)
                         : (m < 72) ? (Wf + (m - 64) * 64 + ks)
                                    : (Wg + (m - 72) * 64 + ks);
        const float scl = (m >= 64 && m < 72) ? 1.44269504088896f : 1.0f;
        f32x4 wv = *(const f32x4*)src;
        *(unsigned*)&WL[m][ks]     = (unsigned)f2bf_rne(wv[0] * scl) | ((unsigned)f2bf_rne(wv[1] * scl) << 16);
        *(unsigned*)&WL[m][ks + 2] = (unsigned)f2bf_rne(wv[2] * scl) | ((unsigned)f2bf_rne(wv[3] * scl) << 16);
    }
    // stage x tile (64c x 64n f32 = 4 x f32x4 per thread), transposed into XT
    #pragma unroll
    for (int r4 = 0; r4 < 4; r4++) {
        int v = r4 * 256 + t;
        int c = v >> 4, ns = (v & 15) << 2;
        f32x4 xv = *(const f32x4*)(xb + (size_t)c * NN + n0 + ns);
        #pragma unroll
        for (int e = 0; e < 4; e++) XT[ns + e][c] = f2bf_rne(xv[e]);
    }
    __syncthreads();

    const int n = n0 + wave * 16 + col;
    s16x8 bfrag[2], afrag[5][2];
    #pragma unroll
    for (int s = 0; s < 2; s++)
        bfrag[s] = *(const s16x8*)&XT[wave * 16 + col][s * 32 + quad * 8];
    #pragma unroll
    for (int mt = 0; mt < 5; mt++)
        #pragma unroll
        for (int s = 0; s < 2; s++)
            afrag[mt][s] = *(const s16x8*)&WL[mt * 16 + col][s * 32 + quad * 8];

    f32x4 d[5];
    #pragma unroll
    for (int mt = 0; mt < 5; mt++) d[mt] = (f32x4){0.f, 0.f, 0.f, 0.f};
    #pragma unroll
    for (int s = 0; s < 2; s++)
        #pragma unroll
        for (int mt = 0; mt < 5; mt++)
            d[mt] = __builtin_amdgcn_mfma_f32_16x16x32_bf16(afrag[mt][s], bfrag[s], d[mt], 0, 0, 0);

    // Q/G rows -> [n][16] padded layout. quad0 -> Q[0..3] (+zeros 8..15),
    // quad1 -> Q[4..7], quad2 -> G[0..3] (+zeros), quad3 -> G[4..7].
    union { s16x4 v; u16 e[4]; } pk4;
    #pragma unroll
    for (int r = 0; r < 4; r++) pk4.e[r] = f2bf_rne(d[4][r]);
    u16* qgbase = (quad < 2 ? Qw : Gw) + ((size_t)b * NN + n) * 16;
    *(s16x4*)(qgbase + (quad & 1) * 4) = pk4.v;
    if ((quad & 1) == 0) {
        s16x8 z;
        #pragma unroll
        for (int q = 0; q < 8; q++) ((u16*)&z)[q] = 0;
        *(s16x8*)(qgbase + 8) = z;
    }

    // H: d[mt][r] = H[c = mt*16+quad*4+r][n]  ->  LDS [c][n_local]
    __syncthreads();                       // all WL/XT fragment reads complete
    u16 (*Hl)[72] = WL;                    // reuse WL space (needs 64x72)
    #pragma unroll
    for (int mt = 0; mt < 4; mt++)
        #pragma unroll
        for (int r = 0; r < 4; r++)
            Hl[mt * 16 + quad * 4 + r][wave * 16 + col] = f2bf_rne(d[mt][r]);
    __syncthreads();

    // fragment-ordered readout + coalesced store (2 x dwordx4 per thread)
    u16* HfB = Hf + (size_t)b * NC * NN + (size_t)blockIdx.x * 4096;
    #pragma unroll
    for (int it = 0; it < 2; it++) {
        int u = it * 256 + t;
        int s_local = u >> 7, chalf = (u >> 6) & 1, l = u & 63;
        s16x8 vv = *(const s16x8*)&Hl[chalf * 32 + (l & 31)][s_local * 16 + (l >> 5) * 8];
        *(s16x8*)(HfB + (size_t)((s_local * 2 + chalf) * 512 + l * 8)) = vv;
    }
}

// ---------------------------------------------------------------------------
// Kernel 2 v6: fused flash attention, barrier-free main loop, COALESCED V.
// Grid (128, 8): block owns 32 i-rows; each of 4 waves independently covers
// j-quarter wave*1024 in 32-j chunks. V fragments come from the
// pre-fragmented Hf layout: one dwordx4 per fragment, 64 lanes = 1KB
// contiguous (fixes round-5 TA saturation: 144 -> 48 lines/chunk/wave).
// PV is mfma(A = P^T (in-register pb), B = V-frag) -> accumulates O^T[i][c];
// pb doubles as A-frag because A/B fragment layouts are symmetric.
// Row-sums as f32 VALU adds; epilogue tree-combines 4 wave partials through
// LDS in O^T layout, scale = gamma/l applied at the store phase.
// ---------------------------------------------------------------------------
__global__ __launch_bounds__(256, 4)
void attention_fused(const u16* __restrict__ Qw, const u16* __restrict__ Gw,
                     const u16* __restrict__ Hf,
                     const float* __restrict__ x, const float* __restrict__ gamma,
                     float* __restrict__ out)
{
    const int b  = blockIdx.y;
    const int i0 = blockIdx.x * 32;
    const int t  = threadIdx.x;
    const int wave = t >> 6, lane = t & 63, col = lane & 31, hi = lane >> 5;

    __shared__ __align__(16) float R0[64][36];   // O^T partials [c][i']
    __shared__ __align__(16) float R1[64][36];
    __shared__ float Ls[4][32];
    __shared__ float Sc[32];

    const u16* Qb  = Qw + (size_t)b * NN * 16;
    const u16* Gb  = Gw + (size_t)b * NN * 16;
    const u16* Hfb = Hf + (size_t)b * NC * NN;

    const float g = gamma[0];

    // Q fragment (B-operand of S^T): B[k=hi*8+kk][n=i=col]; k>=8 zeros
    s16x8 qf = *(const s16x8*)(Qb + (size_t)(i0 + col) * 16 + hi * 8);

    f32x16 oacc[2];                  // oacc[chalf][r] = O^T[i'][c=chalf*32+col]
    oacc[0] = Z16; oacc[1] = Z16;
    float lsum = 0.f;

    const int jbase = wave * 1024;
    const u16* pv = Hfb + (size_t)(jbase >> 4) * 1024 + (size_t)lane * 8;

    // prefetch chunk 0: G A-frag + 4 V B-frags (s2 x chalf)
    s16x8 ga  = *(const s16x8*)(Gb + (size_t)(jbase + col) * 16 + hi * 8);
    s16x8 va0 = *(const s16x8*)(pv);          // s2=0, chalf=0
    s16x8 va1 = *(const s16x8*)(pv + 512);    // s2=0, chalf=1
    s16x8 va2 = *(const s16x8*)(pv + 1024);   // s2=1, chalf=0
    s16x8 va3 = *(const s16x8*)(pv + 1536);   // s2=1, chalf=1
    pv += 2048;

    for (int cc = 0; cc < 32; cc++) {
        // issue prefetch for chunk cc+1 (consumed next iter; last-iter
        // overread lands in the adjacent ws region — benign)
        s16x8 gan = *(const s16x8*)(Gb + (size_t)(jbase + cc * 32 + 32 + col) * 16 + hi * 8);
        s16x8 vn0 = *(const s16x8*)(pv);
        s16x8 vn1 = *(const s16x8*)(pv + 512);
        s16x8 vn2 = *(const s16x8*)(pv + 1024);
        s16x8 vn3 = *(const s16x8*)(pv + 1536);
        pv += 2048;

        f32x16 S = __builtin_amdgcn_mfma_f32_32x32x16_bf16(ga, qf, Z16, 0, 0, 0);
        #pragma unroll
        for (int r = 0; r < 16; r++) S[r] = exp2_hw(S[r]);
        #pragma unroll
        for (int r = 0; r < 16; r++) lsum += S[r];

        #pragma unroll
        for (int s2 = 0; s2 < 2; s2++) {
            unsigned w0 = cvt_pk_bf16(S[8*s2+0], S[8*s2+1]);
            unsigned w2 = cvt_pk_bf16(S[8*s2+4], S[8*s2+5]);
            unsigned w1 = cvt_pk_bf16(S[8*s2+2], S[8*s2+3]);
            unsigned w3 = cvt_pk_bf16(S[8*s2+6], S[8*s2+7]);
            pl32_swap(w0, w2);
            pl32_swap(w1, w3);
            union { s16x8 v; unsigned u[4]; } pb;
            pb.u[0] = w0; pb.u[1] = w1; pb.u[2] = w2; pb.u[3] = w3;
            // pb = P^T A-frag: A[m=i=col][k=hi*8+kk] for this 16-j slice
            oacc[0] = __builtin_amdgcn_mfma_f32_32x32x16_bf16(pb.v, s2 ? va2 : va0, oacc[0], 0, 0, 0);
            oacc[1] = __builtin_amdgcn_mfma_f32_32x32x16_bf16(pb.v, s2 ? va3 : va1, oacc[1], 0, 0, 0);
        }
        ga = gan; va0 = vn0; va1 = vn1; va2 = vn2; va3 = vn3;
    }

    // combine hi-halves of lsum (lane i and i+32 hold disjoint j'-sets)
    {
        unsigned a = __float_as_uint(lsum), c2 = a;
        pl32_swap(a, c2);
        lsum = __uint_as_float(a) + __uint_as_float(c2);
    }

    // ---- epilogue: tree-combine 4 wave partials (O^T layout) ----
    if (hi == 0) Ls[wave][col] = lsum;
    if (wave & 1) {
        float (*R)[36] = (wave == 1) ? R0 : R1;
        #pragma unroll
        for (int ch = 0; ch < 2; ch++)
            #pragma unroll
            for (int r = 0; r < 16; r++)
                R[ch * 32 + col][(r & 3) + 8 * (r >> 2) + 4 * hi] = oacc[ch][r];
    }
    __syncthreads();
    if (!(wave & 1)) {
        float (*R)[36] = (wave == 0) ? R0 : R1;
        #pragma unroll
        for (int ch = 0; ch < 2; ch++)
            #pragma unroll
            for (int r = 0; r < 16; r++)
                oacc[ch][r] += R[ch * 32 + col][(r & 3) + 8 * (r >> 2) + 4 * hi];
    }
    if (wave == 1 && hi == 0)
        Sc[col] = g / (Ls[0][col] + Ls[1][col] + Ls[2][col] + Ls[3][col]);
    if (wave == 2) {
        #pragma unroll
        for (int ch = 0; ch < 2; ch++)
            #pragma unroll
            for (int r = 0; r < 16; r++)
                R1[ch * 32 + col][(r & 3) + 8 * (r >> 2) + 4 * hi] = oacc[ch][r];
    }
    __syncthreads();
    if (wave == 0) {
        #pragma unroll
        for (int ch = 0; ch < 2; ch++)
            #pragma unroll
            for (int r = 0; r < 16; r++) {
                int ii = (r & 3) + 8 * (r >> 2) + 4 * hi;
                R0[ch * 32 + col][ii] = oacc[ch][r] + R1[ch * 32 + col][ii];
            }
    }
    __syncthreads();

    // store: coalesced; scale = gamma/l applied here; residual add
    const int oc = t >> 2, q4 = t & 3;
    f32x4 o0 = *(const f32x4*)&R0[oc][q4 * 8];
    f32x4 o1 = *(const f32x4*)&R0[oc][q4 * 8 + 4];
    const float* xr = x   + ((size_t)b * NC + oc) * NN + i0 + q4 * 8;
    float*    orow  = out + ((size_t)b * NC + oc) * NN + i0 + q4 * 8;
    f32x4 x0 = *(const f32x4*)(xr);
    f32x4 x1 = *(const f32x4*)(xr + 4);
    f32x4 r0, r1;
    #pragma unroll
    for (int e = 0; e < 4; e++) {
        r0[e] = o0[e] * Sc[q4 * 8 + e]     + x0[e];
        r1[e] = o1[e] * Sc[q4 * 8 + 4 + e] + x1[e];
    }
    *(f32x4*)(orow)     = r0;
    *(f32x4*)(orow + 4) = r1;
}

extern "C" void kernel_launch(void* const* d_in, const int* in_sizes, int n_in,
                              void* d_out, int out_size, void* d_ws, size_t ws_size,
                              hipStream_t stream) {
    const float* x     = (const float*)d_in[0];
    const float* Wf    = (const float*)d_in[1];
    const float* Wg    = (const float*)d_in[2];
    const float* Wh    = (const float*)d_in[3];
    const float* gamma = (const float*)d_in[4];
    float* out = (float*)d_out;

    // layout: Hf first, then Gw, then Qw — so last-iteration prefetch
    // overreads (Hf -> Gw, Gw -> Qw) stay inside the workspace.
    u16* Hf = (u16*)d_ws;                       // [B][256 slices][2][512] frag-order
    u16* Gw = Hf + (size_t)NB * NC * NN;        // [B][N][16] (top 8 zeroed)
    u16* Qw = Gw + (size_t)NB * NN * 16;        // [B][N][16] (top 8 zeroed)

    precompute_qgh<<<dim3(64, NB), 256, 0, stream>>>(x, Wf, Wg, Wh, Qw, Gw, Hf);
    attention_fused<<<dim3(128, NB), 256, 0, stream>>>(Qw, Gw, Hf, x, gamma, out);
}

// Round 7
// 105.202 us; speedup vs baseline: 1.3178x; 1.0085x over previous
//
#include <hip/hip_runtime.h>

typedef float f32x4 __attribute__((ext_vector_type(4)));
typedef float f32x16 __attribute__((ext_vector_type(16)));
typedef short s16x8 __attribute__((ext_vector_type(8)));
typedef short s16x4 __attribute__((ext_vector_type(4)));
typedef unsigned short u16;

#define NB 8
#define NC 64
#define NN 4096

// float -> bf16 bits, round-to-nearest-even
__device__ __forceinline__ u16 f2bf_rne(float f) {
    unsigned u = __float_as_uint(f);
    u += 0x7FFFu + ((u >> 16) & 1u);
    return (u16)(u >> 16);
}
__device__ __forceinline__ float bf2f(u16 v) {
    return __uint_as_float(((unsigned)v) << 16);
}
// pack two f32 -> one u32 of 2 bf16 (RNE), lo = first arg
__device__ __forceinline__ unsigned cvt_pk_bf16(float lo, float hi) {
    unsigned r;
    asm("v_cvt_pk_bf16_f32 %0, %1, %2" : "=v"(r) : "v"(lo), "v"(hi));
    return r;
}
// swap: a' = {a.lanes0-31, b.lanes0-31}, b' = {a.lanes32-63, b.lanes32-63}
__device__ __forceinline__ void pl32_swap(unsigned &a, unsigned &b) {
    asm("v_permlane32_swap_b32 %0, %1" : "+v"(a), "+v"(b));
}
// 2^x via the hardware transcendental unit (v_exp_f32)
__device__ __forceinline__ float exp2_hw(float x) {
    return __builtin_amdgcn_exp2f(x);
}

#define Z16 ((f32x16){0.f,0.f,0.f,0.f,0.f,0.f,0.f,0.f,0.f,0.f,0.f,0.f,0.f,0.f,0.f,0.f})

// ---------------------------------------------------------------------------
// Kernel 1: W' = [Wh(64); Wf(8); Wg(8)] (80x64) @ x[b] via MFMA.
// Wf rows pre-scaled by log2(e). Qw/Gw stored [B][N][16] bf16, top 8 zeroed.
// H written in PV-B-FRAGMENT order (Hf) for coalesced attention V loads.
// v7: grid = (b, n-tile) so batch b's blocks land on XCD b (round-robin
// linear%8 mapping) — Hf[b]/G[b]/Q[b] are produced INTO XCD-b's L2, which
// the attention kernel (same mapping) then hits locally.
// ---------------------------------------------------------------------------
__global__ __launch_bounds__(256, 4)
void precompute_qgh(const float* __restrict__ x,
                    const float* __restrict__ Wf,
                    const float* __restrict__ Wg,
                    const float* __restrict__ Wh,
                    u16* __restrict__ Qw, u16* __restrict__ Gw,
                    u16* __restrict__ Hf)
{
    const int b  = blockIdx.x;           // b fastest -> XCD = b
    const int n0 = blockIdx.y * 64;
    const int t  = threadIdx.x;
    const int wave = t >> 6, lane = t & 63, col = lane & 15, quad = lane >> 4;
    const float* xb = x + (size_t)b * NC * NN;

    __shared__ __align__(16) u16 WL[80][72];   // rows 0..63 Wh, 64..71 Wf, 72..79 Wg
    __shared__ __align__(16) u16 XT[64][72];   // x tile transposed: [n_local][c]

    // stage W' (5120 f32 = 5 x f32x4 per thread); Wf scaled by log2(e)
    #pragma unroll
    for (int r5 = 0; r5 < 5; r5++) {
        int v = r5 * 256 + t;
        int m = v >> 4, ks = (v & 15) << 2;
        const float* src = (m < 64) ? (Wh + m * 64 + ks)
                         : (m < 72) ? (Wf + (m - 64) * 64 + ks)
                                    : (Wg + (m - 72) * 64 + ks);
        const float scl = (m >= 64 && m < 72) ? 1.44269504088896f : 1.0f;
        f32x4 wv = *(const f32x4*)src;
        *(unsigned*)&WL[m][ks]     = (unsigned)f2bf_rne(wv[0] * scl) | ((unsigned)f2bf_rne(wv[1] * scl) << 16);
        *(unsigned*)&WL[m][ks + 2] = (unsigned)f2bf_rne(wv[2] * scl) | ((unsigned)f2bf_rne(wv[3] * scl) << 16);
    }
    // stage x tile (64c x 64n f32 = 4 x f32x4 per thread), transposed into XT
    #pragma unroll
    for (int r4 = 0; r4 < 4; r4++) {
        int v = r4 * 256 + t;
        int c = v >> 4, ns = (v & 15) << 2;
        f32x4 xv = *(const f32x4*)(xb + (size_t)c * NN + n0 + ns);
        #pragma unroll
        for (int e = 0; e < 4; e++) XT[ns + e][c] = f2bf_rne(xv[e]);
    }
    __syncthreads();

    const int n = n0 + wave * 16 + col;
    s16x8 bfrag[2], afrag[5][2];
    #pragma unroll
    for (int s = 0; s < 2; s++)
        bfrag[s] = *(const s16x8*)&XT[wave * 16 + col][s * 32 + quad * 8];
    #pragma unroll
    for (int mt = 0; mt < 5; mt++)
        #pragma unroll
        for (int s = 0; s < 2; s++)
            afrag[mt][s] = *(const s16x8*)&WL[mt * 16 + col][s * 32 + quad * 8];

    f32x4 d[5];
    #pragma unroll
    for (int mt = 0; mt < 5; mt++) d[mt] = (f32x4){0.f, 0.f, 0.f, 0.f};
    #pragma unroll
    for (int s = 0; s < 2; s++)
        #pragma unroll
        for (int mt = 0; mt < 5; mt++)
            d[mt] = __builtin_amdgcn_mfma_f32_16x16x32_bf16(afrag[mt][s], bfrag[s], d[mt], 0, 0, 0);

    // Q/G rows -> [n][16] padded layout. quad0 -> Q[0..3] (+zeros 8..15),
    // quad1 -> Q[4..7], quad2 -> G[0..3] (+zeros), quad3 -> G[4..7].
    union { s16x4 v; u16 e[4]; } pk4;
    #pragma unroll
    for (int r = 0; r < 4; r++) pk4.e[r] = f2bf_rne(d[4][r]);
    u16* qgbase = (quad < 2 ? Qw : Gw) + ((size_t)b * NN + n) * 16;
    *(s16x4*)(qgbase + (quad & 1) * 4) = pk4.v;
    if ((quad & 1) == 0) {
        s16x8 z;
        #pragma unroll
        for (int q = 0; q < 8; q++) ((u16*)&z)[q] = 0;
        *(s16x8*)(qgbase + 8) = z;
    }

    // H: d[mt][r] = H[c = mt*16+quad*4+r][n]  ->  LDS [c][n_local]
    __syncthreads();                       // all WL/XT fragment reads complete
    u16 (*Hl)[72] = WL;                    // reuse WL space (needs 64x72)
    #pragma unroll
    for (int mt = 0; mt < 4; mt++)
        #pragma unroll
        for (int r = 0; r < 4; r++)
            Hl[mt * 16 + quad * 4 + r][wave * 16 + col] = f2bf_rne(d[mt][r]);
    __syncthreads();

    // fragment-ordered readout + coalesced store (2 x dwordx4 per thread)
    u16* HfB = Hf + (size_t)b * NC * NN + (size_t)blockIdx.y * 4096;
    #pragma unroll
    for (int it = 0; it < 2; it++) {
        int u = it * 256 + t;
        int s_local = u >> 7, chalf = (u >> 6) & 1, l = u & 63;
        s16x8 vv = *(const s16x8*)&Hl[chalf * 32 + (l & 31)][s_local * 16 + (l >> 5) * 8];
        *(s16x8*)(HfB + (size_t)((s_local * 2 + chalf) * 512 + l * 8)) = vv;
    }
}

// ---------------------------------------------------------------------------
// Kernel 2 v7: fused flash attention, barrier-free main loop, coalesced V,
// BATCH->XCD PINNED. Grid (8, 128): blockIdx.x = b (fastest) so XCD = b;
// per-XCD working set = Hf[b] 512KB + G[b]/Q[b] 256KB < 4MB L2 (round 6 mixed
// all batches on each XCD: 6.2MB working set thrashed to IF/HBM, capping
// read BW at ~15.6 TB/s of the 34.5 TB/s L2 ceiling).
// Per wave: j-quarter in 32-j chunks; register double-buffered G/V frags;
// S^T = mfma32(G,Q); exp2; P in-register (cvt_pk + permlane32_swap);
// PV = mfma(P^T, Vfrag) -> O^T; row-sums as 4-way treed f32 adds.
// Epilogue tree-combines 4 wave partials through LDS, scale gamma/l at store.
// ---------------------------------------------------------------------------
__global__ __launch_bounds__(256, 4)
void attention_fused(const u16* __restrict__ Qw, const u16* __restrict__ Gw,
                     const u16* __restrict__ Hf,
                     const float* __restrict__ x, const float* __restrict__ gamma,
                     float* __restrict__ out)
{
    const int b  = blockIdx.x;           // b fastest -> XCD = b
    const int i0 = blockIdx.y * 32;
    const int t  = threadIdx.x;
    const int wave = t >> 6, lane = t & 63, col = lane & 31, hi = lane >> 5;

    __shared__ __align__(16) float R0[64][36];   // O^T partials [c][i']
    __shared__ __align__(16) float R1[64][36];
    __shared__ float Ls[4][32];
    __shared__ float Sc[32];

    const u16* Qb  = Qw + (size_t)b * NN * 16;
    const u16* Gb  = Gw + (size_t)b * NN * 16;
    const u16* Hfb = Hf + (size_t)b * NC * NN;

    const float g = gamma[0];

    // Q fragment (B-operand of S^T): B[k=hi*8+kk][n=i=col]; k>=8 zeros
    s16x8 qf = *(const s16x8*)(Qb + (size_t)(i0 + col) * 16 + hi * 8);

    f32x16 oacc[2];                  // oacc[chalf][r] = O^T[i'][c=chalf*32+col]
    oacc[0] = Z16; oacc[1] = Z16;
    float ls0 = 0.f, ls1 = 0.f, ls2 = 0.f, ls3 = 0.f;   // treed row-sum accums

    const int jbase = wave * 1024;
    const u16* pv = Hfb + (size_t)(jbase >> 4) * 1024 + (size_t)lane * 8;

    // prefetch chunk 0: G A-frag + 4 V B-frags (s2 x chalf)
    s16x8 ga  = *(const s16x8*)(Gb + (size_t)(jbase + col) * 16 + hi * 8);
    s16x8 va0 = *(const s16x8*)(pv);          // s2=0, chalf=0
    s16x8 va1 = *(const s16x8*)(pv + 512);    // s2=0, chalf=1
    s16x8 va2 = *(const s16x8*)(pv + 1024);   // s2=1, chalf=0
    s16x8 va3 = *(const s16x8*)(pv + 1536);   // s2=1, chalf=1
    pv += 2048;

    for (int cc = 0; cc < 32; cc++) {
        // issue prefetch for chunk cc+1 (consumed next iter; last-iter
        // overread lands in the adjacent ws region — benign)
        s16x8 gan = *(const s16x8*)(Gb + (size_t)(jbase + cc * 32 + 32 + col) * 16 + hi * 8);
        s16x8 vn0 = *(const s16x8*)(pv);
        s16x8 vn1 = *(const s16x8*)(pv + 512);
        s16x8 vn2 = *(const s16x8*)(pv + 1024);
        s16x8 vn3 = *(const s16x8*)(pv + 1536);
        pv += 2048;

        f32x16 S = __builtin_amdgcn_mfma_f32_32x32x16_bf16(ga, qf, Z16, 0, 0, 0);
        #pragma unroll
        for (int r = 0; r < 16; r++) S[r] = exp2_hw(S[r]);
        // 4-way treed partial row-sum (shortens serial FADD chain 16 -> 4)
        #pragma unroll
        for (int r = 0; r < 16; r += 4) {
            ls0 += S[r]; ls1 += S[r + 1]; ls2 += S[r + 2]; ls3 += S[r + 3];
        }

        #pragma unroll
        for (int s2 = 0; s2 < 2; s2++) {
            unsigned w0 = cvt_pk_bf16(S[8*s2+0], S[8*s2+1]);
            unsigned w2 = cvt_pk_bf16(S[8*s2+4], S[8*s2+5]);
            unsigned w1 = cvt_pk_bf16(S[8*s2+2], S[8*s2+3]);
            unsigned w3 = cvt_pk_bf16(S[8*s2+6], S[8*s2+7]);
            pl32_swap(w0, w2);
            pl32_swap(w1, w3);
            union { s16x8 v; unsigned u[4]; } pb;
            pb.u[0] = w0; pb.u[1] = w1; pb.u[2] = w2; pb.u[3] = w3;
            // pb = P^T A-frag: A[m=i=col][k=hi*8+kk] for this 16-j slice
            oacc[0] = __builtin_amdgcn_mfma_f32_32x32x16_bf16(pb.v, s2 ? va2 : va0, oacc[0], 0, 0, 0);
            oacc[1] = __builtin_amdgcn_mfma_f32_32x32x16_bf16(pb.v, s2 ? va3 : va1, oacc[1], 0, 0, 0);
        }
        ga = gan; va0 = vn0; va1 = vn1; va2 = vn2; va3 = vn3;
    }

    float lsum = (ls0 + ls1) + (ls2 + ls3);
    // combine hi-halves of lsum (lane i and i+32 hold disjoint j'-sets)
    {
        unsigned a = __float_as_uint(lsum), c2 = a;
        pl32_swap(a, c2);
        lsum = __uint_as_float(a) + __uint_as_float(c2);
    }

    // ---- epilogue: tree-combine 4 wave partials (O^T layout) ----
    if (hi == 0) Ls[wave][col] = lsum;
    if (wave & 1) {
        float (*R)[36] = (wave == 1) ? R0 : R1;
        #pragma unroll
        for (int ch = 0; ch < 2; ch++)
            #pragma unroll
            for (int r = 0; r < 16; r++)
                R[ch * 32 + col][(r & 3) + 8 * (r >> 2) + 4 * hi] = oacc[ch][r];
    }
    __syncthreads();
    if (!(wave & 1)) {
        float (*R)[36] = (wave == 0) ? R0 : R1;
        #pragma unroll
        for (int ch = 0; ch < 2; ch++)
            #pragma unroll
            for (int r = 0; r < 16; r++)
                oacc[ch][r] += R[ch * 32 + col][(r & 3) + 8 * (r >> 2) + 4 * hi];
    }
    if (wave == 1 && hi == 0)
        Sc[col] = g / (Ls[0][col] + Ls[1][col] + Ls[2][col] + Ls[3][col]);
    if (wave == 2) {
        #pragma unroll
        for (int ch = 0; ch < 2; ch++)
            #pragma unroll
            for (int r = 0; r < 16; r++)
                R1[ch * 32 + col][(r & 3) + 8 * (r >> 2) + 4 * hi] = oacc[ch][r];
    }
    __syncthreads();
    if (wave == 0) {
        #pragma unroll
        for (int ch = 0; ch < 2; ch++)
            #pragma unroll
            for (int r = 0; r < 16; r++) {
                int ii = (r & 3) + 8 * (r >> 2) + 4 * hi;
                R0[ch * 32 + col][ii] = oacc[ch][r] + R1[ch * 32 + col][ii];
            }
    }
    __syncthreads();

    // store: coalesced; scale = gamma/l applied here; residual add
    const int oc = t >> 2, q4 = t & 3;
    f32x4 o0 = *(const f32x4*)&R0[oc][q4 * 8];
    f32x4 o1 = *(const f32x4*)&R0[oc][q4 * 8 + 4];
    const float* xr = x   + ((size_t)b * NC + oc) * NN + i0 + q4 * 8;
    float*    orow  = out + ((size_t)b * NC + oc) * NN + i0 + q4 * 8;
    f32x4 x0 = *(const f32x4*)(xr);
    f32x4 x1 = *(const f32x4*)(xr + 4);
    f32x4 r0, r1;
    #pragma unroll
    for (int e = 0; e < 4; e++) {
        r0[e] = o0[e] * Sc[q4 * 8 + e]     + x0[e];
        r1[e] = o1[e] * Sc[q4 * 8 + 4 + e] + x1[e];
    }
    *(f32x4*)(orow)     = r0;
    *(f32x4*)(orow + 4) = r1;
}

extern "C" void kernel_launch(void* const* d_in, const int* in_sizes, int n_in,
                              void* d_out, int out_size, void* d_ws, size_t ws_size,
                              hipStream_t stream) {
    const float* x     = (const float*)d_in[0];
    const float* Wf    = (const float*)d_in[1];
    const float* Wg    = (const float*)d_in[2];
    const float* Wh    = (const float*)d_in[3];
    const float* gamma = (const float*)d_in[4];
    float* out = (float*)d_out;

    // layout: Hf first, then Gw, then Qw — so last-iteration prefetch
    // overreads (Hf -> Gw, Gw -> Qw) stay inside the workspace.
    u16* Hf = (u16*)d_ws;                       // [B][256 slices][2][512] frag-order
    u16* Gw = Hf + (size_t)NB * NC * NN;        // [B][N][16] (top 8 zeroed)
    u16* Qw = Gw + (size_t)NB * NN * 16;        // [B][N][16] (top 8 zeroed)

    precompute_qgh<<<dim3(NB, 64), 256, 0, stream>>>(x, Wf, Wg, Wh, Qw, Gw, Hf);
    attention_fused<<<dim3(NB, 128), 256, 0, stream>>>(Qw, Gw, Hf, x, gamma, out);
}

// Round 8
// 99.369 us; speedup vs baseline: 1.3951x; 1.0587x over previous
//
#include <hip/hip_runtime.h>

typedef float f32x4 __attribute__((ext_vector_type(4)));
typedef float f32x16 __attribute__((ext_vector_type(16)));
typedef short s16x8 __attribute__((ext_vector_type(8)));
typedef short s16x4 __attribute__((ext_vector_type(4)));
typedef unsigned short u16;

#define NB 8
#define NC 64
#define NN 4096

// float -> bf16 bits, round-to-nearest-even
__device__ __forceinline__ u16 f2bf_rne(float f) {
    unsigned u = __float_as_uint(f);
    u += 0x7FFFu + ((u >> 16) & 1u);
    return (u16)(u >> 16);
}
__device__ __forceinline__ float bf2f(u16 v) {
    return __uint_as_float(((unsigned)v) << 16);
}
// pack two f32 -> one u32 of 2 bf16 (RNE), lo = first arg
__device__ __forceinline__ unsigned cvt_pk_bf16(float lo, float hi) {
    unsigned r;
    asm("v_cvt_pk_bf16_f32 %0, %1, %2" : "=v"(r) : "v"(lo), "v"(hi));
    return r;
}
// swap: a' = {a.lanes0-31, b.lanes0-31}, b' = {a.lanes32-63, b.lanes32-63}
__device__ __forceinline__ void pl32_swap(unsigned &a, unsigned &b) {
    asm("v_permlane32_swap_b32 %0, %1" : "+v"(a), "+v"(b));
}
// 2^x via the hardware transcendental unit (v_exp_f32)
__device__ __forceinline__ float exp2_hw(float x) {
    return __builtin_amdgcn_exp2f(x);
}

#define Z16 ((f32x16){0.f,0.f,0.f,0.f,0.f,0.f,0.f,0.f,0.f,0.f,0.f,0.f,0.f,0.f,0.f,0.f})

// ---------------------------------------------------------------------------
// Kernel 1 (unchanged from v7): W' = [Wh(64); Wf(8); Wg(8)] @ x[b] via MFMA.
// Wf pre-scaled by log2(e). Qw/Gw: [B][N][16] bf16, top 8 zeroed. H written
// in PV-B-fragment order (Hf). Grid (b, n-tile) -> batch b pinned to XCD b.
// ---------------------------------------------------------------------------
__global__ __launch_bounds__(256, 4)
void precompute_qgh(const float* __restrict__ x,
                    const float* __restrict__ Wf,
                    const float* __restrict__ Wg,
                    const float* __restrict__ Wh,
                    u16* __restrict__ Qw, u16* __restrict__ Gw,
                    u16* __restrict__ Hf)
{
    const int b  = blockIdx.x;           // b fastest -> XCD = b
    const int n0 = blockIdx.y * 64;
    const int t  = threadIdx.x;
    const int wave = t >> 6, lane = t & 63, col = lane & 15, quad = lane >> 4;
    const float* xb = x + (size_t)b * NC * NN;

    __shared__ __align__(16) u16 WL[80][72];
    __shared__ __align__(16) u16 XT[64][72];

    #pragma unroll
    for (int r5 = 0; r5 < 5; r5++) {
        int v = r5 * 256 + t;
        int m = v >> 4, ks = (v & 15) << 2;
        const float* src = (m < 64) ? (Wh + m * 64 + ks)
                         : (m < 72) ? (Wf + (m - 64) * 64 + ks)
                                    : (Wg + (m - 72) * 64 + ks);
        const float scl = (m >= 64 && m < 72) ? 1.44269504088896f : 1.0f;
        f32x4 wv = *(const f32x4*)src;
        *(unsigned*)&WL[m][ks]     = (unsigned)f2bf_rne(wv[0] * scl) | ((unsigned)f2bf_rne(wv[1] * scl) << 16);
        *(unsigned*)&WL[m][ks + 2] = (unsigned)f2bf_rne(wv[2] * scl) | ((unsigned)f2bf_rne(wv[3] * scl) << 16);
    }
    #pragma unroll
    for (int r4 = 0; r4 < 4; r4++) {
        int v = r4 * 256 + t;
        int c = v >> 4, ns = (v & 15) << 2;
        f32x4 xv = *(const f32x4*)(xb + (size_t)c * NN + n0 + ns);
        #pragma unroll
        for (int e = 0; e < 4; e++) XT[ns + e][c] = f2bf_rne(xv[e]);
    }
    __syncthreads();

    const int n = n0 + wave * 16 + col;
    s16x8 bfrag[2], afrag[5][2];
    #pragma unroll
    for (int s = 0; s < 2; s++)
        bfrag[s] = *(const s16x8*)&XT[wave * 16 + col][s * 32 + quad * 8];
    #pragma unroll
    for (int mt = 0; mt < 5; mt++)
        #pragma unroll
        for (int s = 0; s < 2; s++)
            afrag[mt][s] = *(const s16x8*)&WL[mt * 16 + col][s * 32 + quad * 8];

    f32x4 d[5];
    #pragma unroll
    for (int mt = 0; mt < 5; mt++) d[mt] = (f32x4){0.f, 0.f, 0.f, 0.f};
    #pragma unroll
    for (int s = 0; s < 2; s++)
        #pragma unroll
        for (int mt = 0; mt < 5; mt++)
            d[mt] = __builtin_amdgcn_mfma_f32_16x16x32_bf16(afrag[mt][s], bfrag[s], d[mt], 0, 0, 0);

    union { s16x4 v; u16 e[4]; } pk4;
    #pragma unroll
    for (int r = 0; r < 4; r++) pk4.e[r] = f2bf_rne(d[4][r]);
    u16* qgbase = (quad < 2 ? Qw : Gw) + ((size_t)b * NN + n) * 16;
    *(s16x4*)(qgbase + (quad & 1) * 4) = pk4.v;
    if ((quad & 1) == 0) {
        s16x8 z;
        #pragma unroll
        for (int q = 0; q < 8; q++) ((u16*)&z)[q] = 0;
        *(s16x8*)(qgbase + 8) = z;
    }

    __syncthreads();
    u16 (*Hl)[72] = WL;                    // reuse WL space
    #pragma unroll
    for (int mt = 0; mt < 4; mt++)
        #pragma unroll
        for (int r = 0; r < 4; r++)
            Hl[mt * 16 + quad * 4 + r][wave * 16 + col] = f2bf_rne(d[mt][r]);
    __syncthreads();

    u16* HfB = Hf + (size_t)b * NC * NN + (size_t)blockIdx.y * 4096;
    #pragma unroll
    for (int it = 0; it < 2; it++) {
        int u = it * 256 + t;
        int s_local = u >> 7, chalf = (u >> 6) & 1, l = u & 63;
        s16x8 vv = *(const s16x8*)&Hl[chalf * 32 + (l & 31)][s_local * 16 + (l >> 5) * 8];
        *(s16x8*)(HfB + (size_t)((s_local * 2 + chalf) * 512 + l * 8)) = vv;
    }
}

// ---------------------------------------------------------------------------
// Kernel 2 v8: fused flash attention, 2 Q-TILES PER WAVE (64 i per block).
// Grid (8, 64), batch->XCD pinned. Each wave: j-quarter, 32-j chunks, TWO
// Q fragments -> G/V fragment loads amortized over 2x the MFMAs (per-XCD L2
// read halves 80 -> 40 MB; round 7 was ~2x above the 19 µs L2-BW floor).
// 2 blocks/CU (2 waves/SIMD) but per-wave ILP doubles.
// Epilogue: per-tile 4-partial tree combine through LDS (4 slabs), scale
// gamma/l at store, residual add, f32 out.
// ---------------------------------------------------------------------------
__global__ __launch_bounds__(256, 2)
void attention_fused(const u16* __restrict__ Qw, const u16* __restrict__ Gw,
                     const u16* __restrict__ Hf,
                     const float* __restrict__ x, const float* __restrict__ gamma,
                     float* __restrict__ out)
{
    const int b  = blockIdx.x;           // b fastest -> XCD = b
    const int i0 = blockIdx.y * 64;
    const int t  = threadIdx.x;
    const int wave = t >> 6, lane = t & 63, col = lane & 31, hi = lane >> 5;

    __shared__ __align__(16) float R0a[64][36];   // tile0 slabs
    __shared__ __align__(16) float R1a[64][36];
    __shared__ __align__(16) float R0b[64][36];   // tile1 slabs
    __shared__ __align__(16) float R1b[64][36];
    __shared__ float Ls[2][4][32];
    __shared__ float Sc[2][32];

    const u16* Qb  = Qw + (size_t)b * NN * 16;
    const u16* Gb  = Gw + (size_t)b * NN * 16;
    const u16* Hfb = Hf + (size_t)b * NC * NN;

    const float g = gamma[0];

    // Two Q fragments: B[k=hi*8+kk][n=i]; k>=8 zeros from layout
    s16x8 qf0 = *(const s16x8*)(Qb + (size_t)(i0 + col) * 16 + hi * 8);
    s16x8 qf1 = *(const s16x8*)(Qb + (size_t)(i0 + 32 + col) * 16 + hi * 8);

    f32x16 oacc[2][2];   // [tile][chalf]; all indexing statically unrolled
    oacc[0][0] = Z16; oacc[0][1] = Z16; oacc[1][0] = Z16; oacc[1][1] = Z16;
    float ls0a = 0.f, ls0b = 0.f, ls1a = 0.f, ls1b = 0.f;

    const int jbase = wave * 1024;
    const u16* pv = Hfb + (size_t)(jbase >> 4) * 1024 + (size_t)lane * 8;

    // prefetch chunk 0: G A-frag + 4 V B-frags ([slice s2][chalf])
    s16x8 ga  = *(const s16x8*)(Gb + (size_t)(jbase + col) * 16 + hi * 8);
    s16x8 va0 = *(const s16x8*)(pv);
    s16x8 va1 = *(const s16x8*)(pv + 512);
    s16x8 va2 = *(const s16x8*)(pv + 1024);
    s16x8 va3 = *(const s16x8*)(pv + 1536);
    pv += 2048;

    for (int cc = 0; cc < 32; cc++) {
        // prefetch chunk cc+1 (last-iter overread -> adjacent ws region, benign)
        s16x8 gan = *(const s16x8*)(Gb + (size_t)(jbase + cc * 32 + 32 + col) * 16 + hi * 8);
        s16x8 vn0 = *(const s16x8*)(pv);
        s16x8 vn1 = *(const s16x8*)(pv + 512);
        s16x8 vn2 = *(const s16x8*)(pv + 1024);
        s16x8 vn3 = *(const s16x8*)(pv + 1536);
        pv += 2048;

        f32x16 S0 = __builtin_amdgcn_mfma_f32_32x32x16_bf16(ga, qf0, Z16, 0, 0, 0);
        f32x16 S1 = __builtin_amdgcn_mfma_f32_32x32x16_bf16(ga, qf1, Z16, 0, 0, 0);
        #pragma unroll
        for (int r = 0; r < 16; r++) S0[r] = exp2_hw(S0[r]);
        #pragma unroll
        for (int r = 0; r < 16; r++) S1[r] = exp2_hw(S1[r]);
        #pragma unroll
        for (int r = 0; r < 16; r += 2) {
            ls0a += S0[r]; ls0b += S0[r + 1];
            ls1a += S1[r]; ls1b += S1[r + 1];
        }

        #pragma unroll
        for (int s2 = 0; s2 < 2; s2++) {
            // tile 0 P fragment
            unsigned a0 = cvt_pk_bf16(S0[8*s2+0], S0[8*s2+1]);
            unsigned a2 = cvt_pk_bf16(S0[8*s2+4], S0[8*s2+5]);
            unsigned a1 = cvt_pk_bf16(S0[8*s2+2], S0[8*s2+3]);
            unsigned a3 = cvt_pk_bf16(S0[8*s2+6], S0[8*s2+7]);
            pl32_swap(a0, a2);
            pl32_swap(a1, a3);
            union { s16x8 v; unsigned u[4]; } p0;
            p0.u[0] = a0; p0.u[1] = a1; p0.u[2] = a2; p0.u[3] = a3;
            // tile 1 P fragment
            unsigned b0 = cvt_pk_bf16(S1[8*s2+0], S1[8*s2+1]);
            unsigned b2 = cvt_pk_bf16(S1[8*s2+4], S1[8*s2+5]);
            unsigned b1 = cvt_pk_bf16(S1[8*s2+2], S1[8*s2+3]);
            unsigned b3 = cvt_pk_bf16(S1[8*s2+6], S1[8*s2+7]);
            pl32_swap(b0, b2);
            pl32_swap(b1, b3);
            union { s16x8 v; unsigned u[4]; } p1;
            p1.u[0] = b0; p1.u[1] = b1; p1.u[2] = b2; p1.u[3] = b3;
            // V fragments shared by both tiles
            oacc[0][0] = __builtin_amdgcn_mfma_f32_32x32x16_bf16(p0.v, s2 ? va2 : va0, oacc[0][0], 0, 0, 0);
            oacc[0][1] = __builtin_amdgcn_mfma_f32_32x32x16_bf16(p0.v, s2 ? va3 : va1, oacc[0][1], 0, 0, 0);
            oacc[1][0] = __builtin_amdgcn_mfma_f32_32x32x16_bf16(p1.v, s2 ? va2 : va0, oacc[1][0], 0, 0, 0);
            oacc[1][1] = __builtin_amdgcn_mfma_f32_32x32x16_bf16(p1.v, s2 ? va3 : va1, oacc[1][1], 0, 0, 0);
        }
        ga = gan; va0 = vn0; va1 = vn1; va2 = vn2; va3 = vn3;
    }

    float lsum0 = ls0a + ls0b;
    float lsum1 = ls1a + ls1b;
    // combine hi-halves (lane i and i+32 hold disjoint j'-sets)
    {
        unsigned a = __float_as_uint(lsum0), c2 = a;
        pl32_swap(a, c2);
        lsum0 = __uint_as_float(a) + __uint_as_float(c2);
        unsigned d = __float_as_uint(lsum1), e2 = d;
        pl32_swap(d, e2);
        lsum1 = __uint_as_float(d) + __uint_as_float(e2);
    }

    // ---- epilogue: per-tile tree-combine of 4 wave partials (O^T layout) ----
    if (hi == 0) { Ls[0][wave][col] = lsum0; Ls[1][wave][col] = lsum1; }
    if (wave & 1) {
        float (*Ra)[36] = (wave == 1) ? R0a : R1a;
        float (*Rb)[36] = (wave == 1) ? R0b : R1b;
        #pragma unroll
        for (int ch = 0; ch < 2; ch++)
            #pragma unroll
            for (int r = 0; r < 16; r++) {
                int ii = (r & 3) + 8 * (r >> 2) + 4 * hi;
                Ra[ch * 32 + col][ii] = oacc[0][ch][r];
                Rb[ch * 32 + col][ii] = oacc[1][ch][r];
            }
    }
    __syncthreads();
    if (!(wave & 1)) {
        float (*Ra)[36] = (wave == 0) ? R0a : R1a;
        float (*Rb)[36] = (wave == 0) ? R0b : R1b;
        #pragma unroll
        for (int ch = 0; ch < 2; ch++)
            #pragma unroll
            for (int r = 0; r < 16; r++) {
                int ii = (r & 3) + 8 * (r >> 2) + 4 * hi;
                oacc[0][ch][r] += Ra[ch * 32 + col][ii];
                oacc[1][ch][r] += Rb[ch * 32 + col][ii];
            }
    }
    if (wave == 1 && hi == 0)
        Sc[0][col] = g / (Ls[0][0][col] + Ls[0][1][col] + Ls[0][2][col] + Ls[0][3][col]);
    if (wave == 3 && hi == 0)
        Sc[1][col] = g / (Ls[1][0][col] + Ls[1][1][col] + Ls[1][2][col] + Ls[1][3][col]);
    if (wave == 2) {
        #pragma unroll
        for (int ch = 0; ch < 2; ch++)
            #pragma unroll
            for (int r = 0; r < 16; r++) {
                int ii = (r & 3) + 8 * (r >> 2) + 4 * hi;
                R1a[ch * 32 + col][ii] = oacc[0][ch][r];
                R1b[ch * 32 + col][ii] = oacc[1][ch][r];
            }
    }
    __syncthreads();
    if (wave == 0) {
        #pragma unroll
        for (int ch = 0; ch < 2; ch++)
            #pragma unroll
            for (int r = 0; r < 16; r++) {
                int ii = (r & 3) + 8 * (r >> 2) + 4 * hi;
                R0a[ch * 32 + col][ii] = oacc[0][ch][r] + R1a[ch * 32 + col][ii];
                R0b[ch * 32 + col][ii] = oacc[1][ch][r] + R1b[ch * 32 + col][ii];
            }
    }
    __syncthreads();

    // store: 64 c x 64 i; tile uniform per thread (q<2 -> tile0)
    const int oc = t >> 2, q = t & 3;
    float (*slab)[36] = (q < 2) ? R0a : R0b;
    const float* sc = Sc[q >> 1];
    const float* xr = x   + ((size_t)b * NC + oc) * NN + i0;
    float*    orow  = out + ((size_t)b * NC + oc) * NN + i0;
    #pragma unroll
    for (int e = 0; e < 4; e++) {
        const int il = q * 16 + e * 4;        // 0..63 within block's i-range
        const int ii = (q & 1) * 16 + e * 4;  // 0..31 within tile
        f32x4 o = *(const f32x4*)&slab[oc][ii];
        f32x4 xv = *(const f32x4*)(xr + il);
        f32x4 rv;
        #pragma unroll
        for (int k = 0; k < 4; k++) rv[k] = o[k] * sc[ii + k] + xv[k];
        *(f32x4*)(orow + il) = rv;
    }
}

extern "C" void kernel_launch(void* const* d_in, const int* in_sizes, int n_in,
                              void* d_out, int out_size, void* d_ws, size_t ws_size,
                              hipStream_t stream) {
    const float* x     = (const float*)d_in[0];
    const float* Wf    = (const float*)d_in[1];
    const float* Wg    = (const float*)d_in[2];
    const float* Wh    = (const float*)d_in[3];
    const float* gamma = (const float*)d_in[4];
    float* out = (float*)d_out;

    // layout: Hf first, then Gw, then Qw — so last-iteration prefetch
    // overreads (Hf -> Gw, Gw -> Qw) stay inside the workspace.
    u16* Hf = (u16*)d_ws;                       // [B][256 slices][2][512] frag-order
    u16* Gw = Hf + (size_t)NB * NC * NN;        // [B][N][16] (top 8 zeroed)
    u16* Qw = Gw + (size_t)NB * NN * 16;        // [B][N][16] (top 8 zeroed)

    precompute_qgh<<<dim3(NB, 64), 256, 0, stream>>>(x, Wf, Wg, Wh, Qw, Gw, Hf);
    attention_fused<<<dim3(NB, 64), 256, 0, stream>>>(Qw, Gw, Hf, x, gamma, out);
}